// Round 1
// baseline (209.283 us; speedup 1.0000x reference)
//
#include <hip/hip_runtime.h>
#include <hip/hip_bf16.h>
#include <stdint.h>

#define B_ 2
#define T_ 2048
#define C_ 1024
#define H_ 16
#define HD_ 64
#define BT_ (B_*T_)      // 4096 rows
#define N1_ (3*C_)       // 3072

typedef unsigned short u16;
typedef __attribute__((ext_vector_type(8))) short bf16x8;
typedef __attribute__((ext_vector_type(4))) float f32x4;

__device__ __forceinline__ u16 f2bf(float f) {
  __hip_bfloat16 h = __float2bfloat16(f);
  return *reinterpret_cast<u16*>(&h);
}

__device__ __forceinline__ void gload_lds16(const void* g, void* l) {
  __builtin_amdgcn_global_load_lds(
      (const __attribute__((address_space(1))) uint32_t*)g,
      (__attribute__((address_space(3))) uint32_t*)l, 16, 0, 0);
}

// ---------------- cast x: fp32 -> bf16 ----------------
__global__ void cast_f32_bf16_k(const float* __restrict__ in, u16* __restrict__ out, int n) {
  int idx = (blockIdx.x * blockDim.x + threadIdx.x) * 4;
  if (idx >= n) return;
  float4 v = *reinterpret_cast<const float4*>(in + idx);
  u16 tmp[4] = {f2bf(v.x), f2bf(v.y), f2bf(v.z), f2bf(v.w)};
  *reinterpret_cast<uint2*>(out + idx) = *reinterpret_cast<const uint2*>(tmp);
}

// ---------------- transpose+cast: w (K x N fp32) -> wt (N x K bf16) ----------------
__global__ void transcast_k(const float* __restrict__ w, u16* __restrict__ wt, int K, int N) {
  __shared__ float tile[32][33];
  int n0 = blockIdx.x * 32, k0 = blockIdx.y * 32;
  int tx = threadIdx.x, ty = threadIdx.y;   // block (32,8)
#pragma unroll
  for (int i = 0; i < 4; i++)
    tile[ty + i*8][tx] = w[(size_t)(k0 + ty + i*8) * N + n0 + tx];
  __syncthreads();
#pragma unroll
  for (int i = 0; i < 4; i++)
    wt[(size_t)(n0 + ty + i*8) * K + k0 + tx] = f2bf(tile[tx][ty + i*8]);
}

// ---------------- GEMM: A (M x K bf16), Bt (N x K bf16) -> C (M x N) ----------------
template<int OUTF32>
__global__ __launch_bounds__(256) void gemm_bt(const u16* __restrict__ A, const u16* __restrict__ Bt,
                                               void* __restrict__ Cv, int M, int N, int K) {
  __shared__ u16 As[128*32];
  __shared__ u16 Bs[128*32];
  int tid = threadIdx.x, wave = tid >> 6, lane = tid & 63;
  int m0 = blockIdx.y * 128, n0 = blockIdx.x * 128;
  int wm = (wave >> 1) * 64, wn = (wave & 1) * 64;
  f32x4 acc[4][4] = {};
  int srow = lane >> 2, scol = (lane & 3) * 8;           // staging: 4 lanes per 32-elem row
  int fro  = (lane & 15) * 32 + (lane >> 4) * 8;         // fragment read offset

  for (int k0 = 0; k0 < K; k0 += 32) {
    __syncthreads();
#pragma unroll
    for (int i = 0; i < 2; i++) {
      gload_lds16(A  + (size_t)(m0 + i*64 + wave*16 + srow) * K + k0 + scol, &As[(i*64 + wave*16) * 32]);
      gload_lds16(Bt + (size_t)(n0 + i*64 + wave*16 + srow) * K + k0 + scol, &Bs[(i*64 + wave*16) * 32]);
    }
    asm volatile("s_waitcnt vmcnt(0)" ::: "memory");
    __syncthreads();
    bf16x8 af[4], bfr[4];
#pragma unroll
    for (int i = 0; i < 4; i++) af[i]  = *reinterpret_cast<const bf16x8*>(&As[(wm + i*16)*32 + fro]);
#pragma unroll
    for (int j = 0; j < 4; j++) bfr[j] = *reinterpret_cast<const bf16x8*>(&Bs[(wn + j*16)*32 + fro]);
#pragma unroll
    for (int i = 0; i < 4; i++)
#pragma unroll
      for (int j = 0; j < 4; j++)
        acc[i][j] = __builtin_amdgcn_mfma_f32_16x16x32_bf16(af[i], bfr[j], acc[i][j], 0, 0, 0);
  }
  int rg = (lane >> 4) * 4, cq = lane & 15;
#pragma unroll
  for (int i = 0; i < 4; i++)
#pragma unroll
    for (int j = 0; j < 4; j++) {
      size_t basei = (size_t)(m0 + wm + i*16 + rg) * N + (size_t)(n0 + wn + j*16 + cq);
#pragma unroll
      for (int r = 0; r < 4; r++) {
        if constexpr (OUTF32) ((float*)Cv)[basei + (size_t)r * N] = acc[i][j][r];
        else                  ((u16*)Cv)[basei + (size_t)r * N]   = f2bf(acc[i][j][r]);
      }
    }
}

// ---------------- causal flash attention ----------------
// qkv: (B*T, 3C) bf16 rows; per head h: Q cols [h*64,..), K cols [C+h*64,..), V cols [2C+h*64,..)
// Grid: (T/64, B*H), 256 threads = 4 waves, each wave owns 16 query rows.
__global__ __launch_bounds__(256) void attn_kernel(const u16* __restrict__ qkv, u16* __restrict__ attnout) {
  __shared__ u16 Ks[32*64];    // [key][d] linear (global_load_lds)
  __shared__ u16 Vt[64*32];    // [d][key^swz] transposed, xor-swizzled
  __shared__ u16 Pl[4*16*32];  // per-wave P [q][key]
  int tid = threadIdx.x;
  int wave = tid >> 6, lane = tid & 63;
  int lq = lane & 15, lg = lane >> 4;
  int bh = blockIdx.y;
  int b = bh >> 4, h = bh & 15;
  int q64 = blockIdx.x * 64;
  int qbase = q64 + wave * 16;
  const u16* base = qkv + (size_t)b * T_ * N1_;

  // Q fragments: lane holds row q=qbase+lq, dims (chunk*32 + lg*8 + j)
  const u16* qrow = base + (size_t)(qbase + lq) * N1_ + h * HD_;
  bf16x8 qf0 = *reinterpret_cast<const bf16x8*>(qrow + lg * 8);
  bf16x8 qf1 = *reinterpret_cast<const bf16x8*>(qrow + 32 + lg * 8);

  float m_run = -__builtin_inff();
  float l_run = 0.f;
  f32x4 oacc[4] = {};

  int nkt = q64 / 32 + 2;                       // key tiles of 32, causal bound
  int skey = tid >> 3, sd = (tid & 7) * 8;      // V staging mapping
  const u16* krowg = base + C_ + h * HD_ + (size_t)(wave*8 + (lane>>3)) * N1_ + (lane & 7) * 8;

  for (int kt = 0; kt < nkt; kt++) {
    int kb = kt * 32;
    __syncthreads();
    // stage K tile (32x64) via direct-to-LDS
    gload_lds16(krowg + (size_t)kb * N1_, &Ks[wave * 512]);
    // stage V tile transposed with xor swizzle (write ~2-way conflict)
    {
      const u16* gV = base + (size_t)(kb + skey) * N1_ + 2*C_ + h*HD_ + sd;
      bf16x8 v = *reinterpret_cast<const bf16x8*>(gV);
#pragma unroll
      for (int j = 0; j < 8; j++) {
        int d = sd + j;
        Vt[d*32 + (skey ^ ((((d>>3)&3))<<3))] = ((const u16*)&v)[j];
      }
    }
    asm volatile("s_waitcnt vmcnt(0)" ::: "memory");
    __syncthreads();

    // S^T = K * Q^T : C-layout row = key-in-tile, col = query
    f32x4 st[2];
#pragma unroll
    for (int sub = 0; sub < 2; sub++) {
      bf16x8 kf0 = *reinterpret_cast<const bf16x8*>(&Ks[(sub*16 + lq)*64 + lg*8]);
      bf16x8 kf1 = *reinterpret_cast<const bf16x8*>(&Ks[(sub*16 + lq)*64 + 32 + lg*8]);
      f32x4 z = {0.f, 0.f, 0.f, 0.f};
      z = __builtin_amdgcn_mfma_f32_16x16x32_bf16(kf0, qf0, z, 0, 0, 0);
      z = __builtin_amdgcn_mfma_f32_16x16x32_bf16(kf1, qf1, z, 0, 0, 0);
      st[sub] = z;
    }

    // scale + causal mask + online softmax (query = lq, keys across lg*4+r and sub)
    int qg = qbase + lq;
    float sc[2][4];
    float tmax = -__builtin_inff();
#pragma unroll
    for (int sub = 0; sub < 2; sub++)
#pragma unroll
      for (int r = 0; r < 4; r++) {
        float s = st[sub][r] * 0.125f;
        int keyg = kb + sub*16 + lg*4 + r;
        if (keyg > qg) s = -__builtin_inff();
        sc[sub][r] = s;
        tmax = fmaxf(tmax, s);
      }
    tmax = fmaxf(tmax, __shfl_xor(tmax, 16));
    tmax = fmaxf(tmax, __shfl_xor(tmax, 32));
    float mnew = fmaxf(m_run, tmax);
    float resc = __expf(m_run - mnew);
    float tsum = 0.f;
#pragma unroll
    for (int sub = 0; sub < 2; sub++)
#pragma unroll
      for (int r = 0; r < 4; r++) {
        float p = __expf(sc[sub][r] - mnew);
        tsum += p;
        Pl[wave*512 + lq*32 + sub*16 + lg*4 + r] = f2bf(p);
      }
    tsum += __shfl_xor(tsum, 16);
    tsum += __shfl_xor(tsum, 32);
    l_run = l_run * resc + tsum;
    m_run = mnew;

    // rescale O accumulators: O row = query = lg*4 + r -> fetch resc per reg
    float rq[4];
#pragma unroll
    for (int r = 0; r < 4; r++) rq[r] = __shfl(resc, lg*4 + r);
#pragma unroll
    for (int dt = 0; dt < 4; dt++)
#pragma unroll
      for (int r = 0; r < 4; r++) oacc[dt][r] *= rq[r];

    // O += P * V : A-frag = P[q=lq][keys lg*8..+7]; B-frag from Vt (col d, keys)
    bf16x8 pa = *reinterpret_cast<const bf16x8*>(&Pl[wave*512 + lq*32 + lg*8]);
#pragma unroll
    for (int dt = 0; dt < 4; dt++) {
      int d = dt*16 + lq;
      bf16x8 vf = *reinterpret_cast<const bf16x8*>(&Vt[d*32 + ((lg*8) ^ ((((d>>3)&3))<<3))]);
      oacc[dt] = __builtin_amdgcn_mfma_f32_16x16x32_bf16(pa, vf, oacc[dt], 0, 0, 0);
    }
  }

  // epilogue: divide by row sum, write bf16 attn output (B*T, C)
  float linv[4];
#pragma unroll
  for (int r = 0; r < 4; r++) linv[r] = 1.f / __shfl(l_run, lg*4 + r);
#pragma unroll
  for (int dt = 0; dt < 4; dt++)
#pragma unroll
    for (int r = 0; r < 4; r++) {
      size_t row = (size_t)(b*T_ + qbase + lg*4 + r);
      attnout[row * C_ + h*HD_ + dt*16 + lq] = f2bf(oacc[dt][r] * linv[r]);
    }
}

extern "C" void kernel_launch(void* const* d_in, const int* in_sizes, int n_in,
                              void* d_out, int out_size, void* d_ws, size_t ws_size,
                              hipStream_t stream) {
  const float* x     = (const float*)d_in[0];
  const float* w_qkv = (const float*)d_in[1];
  const float* w_out = (const float*)d_in[2];
  float* out = (float*)d_out;
  char* ws = (char*)d_ws;
  // workspace layout (48 MB total)
  u16* xb    = (u16*)(ws);                         // 8 MB  : x bf16 (4096 x 1024)
  u16* wqkvT = (u16*)(ws + ((size_t)8  << 20));    // 6 MB  : w_qkv^T bf16 (3072 x 1024)
  u16* woutT = (u16*)(ws + ((size_t)14 << 20));    // 2 MB  : w_out^T bf16 (1024 x 1024)
  u16* qkvb  = (u16*)(ws + ((size_t)16 << 20));    // 24 MB : qkv bf16 (4096 x 3072)
  u16* attnb = (u16*)(ws + ((size_t)40 << 20));    // 8 MB  : attn out bf16 (4096 x 1024)

  cast_f32_bf16_k<<<(BT_*C_)/1024, 256, 0, stream>>>(x, xb, BT_*C_);
  transcast_k<<<dim3(N1_/32, C_/32), dim3(32, 8), 0, stream>>>(w_qkv, wqkvT, C_, N1_);
  transcast_k<<<dim3(C_/32, C_/32), dim3(32, 8), 0, stream>>>(w_out, woutT, C_, C_);
  gemm_bt<0><<<dim3(N1_/128, BT_/128), 256, 0, stream>>>(xb, wqkvT, (void*)qkvb, BT_, N1_, C_);
  attn_kernel<<<dim3(T_/64, B_*H_), 256, 0, stream>>>(qkvb, attnb);
  gemm_bt<1><<<dim3(C_/128, BT_/128), 256, 0, stream>>>(attnb, woutT, (void*)out, BT_, C_, C_);
}

// Round 4
// 168.809 us; speedup vs baseline: 1.2398x; 1.2398x over previous
//
#include <hip/hip_runtime.h>
#include <hip/hip_bf16.h>
#include <stdint.h>

#define B_ 2
#define T_ 2048
#define C_ 1024
#define H_ 16
#define HD_ 64
#define BT_ (B_*T_)      // 4096 rows
#define N1_ (3*C_)       // 3072

typedef unsigned short u16;
typedef uint32_t u32;
typedef __attribute__((ext_vector_type(8))) short bf16x8;
typedef __attribute__((ext_vector_type(4))) float f32x4;

__device__ __forceinline__ u16 f2bf(float f) {
  __hip_bfloat16 h = __float2bfloat16(f);
  return *reinterpret_cast<u16*>(&h);
}

__device__ __forceinline__ void gload_lds16(const void* g, void* l) {
  __builtin_amdgcn_global_load_lds(
      (const __attribute__((address_space(1))) uint32_t*)g,
      (__attribute__((address_space(3))) uint32_t*)l, 16, 0, 0);
}

// ---------------- cast x: fp32 -> bf16 ----------------
__global__ void cast_f32_bf16_k(const float* __restrict__ in, u16* __restrict__ out, int n) {
  int idx = (blockIdx.x * blockDim.x + threadIdx.x) * 4;
  if (idx >= n) return;
  float4 v = *reinterpret_cast<const float4*>(in + idx);
  u16 tmp[4] = {f2bf(v.x), f2bf(v.y), f2bf(v.z), f2bf(v.w)};
  *reinterpret_cast<uint2*>(out + idx) = *reinterpret_cast<const uint2*>(tmp);
}

// ---------------- transpose+cast: w (K x N fp32) -> wt (N x K bf16) ----------------
__global__ void transcast_k(const float* __restrict__ w, u16* __restrict__ wt, int K, int N) {
  __shared__ float tile[32][33];
  int n0 = blockIdx.x * 32, k0 = blockIdx.y * 32;
  int tx = threadIdx.x, ty = threadIdx.y;   // block (32,8)
#pragma unroll
  for (int i = 0; i < 4; i++)
    tile[ty + i*8][tx] = w[(size_t)(k0 + ty + i*8) * N + n0 + tx];
  __syncthreads();
#pragma unroll
  for (int i = 0; i < 4; i++)
    wt[(size_t)(n0 + ty + i*8) * K + k0 + tx] = f2bf(tile[tx][ty + i*8]);
}

// ---------------- GEMM: A (M x K bf16), Bt (N x K bf16) -> C (M x N) ----------------
template<int OUTF32>
__global__ __launch_bounds__(256) void gemm_bt(const u16* __restrict__ A, const u16* __restrict__ Bt,
                                               void* __restrict__ Cv, int M, int N, int K) {
  __shared__ u16 As[128*32];
  __shared__ u16 Bs[128*32];
  int tid = threadIdx.x, wave = tid >> 6, lane = tid & 63;
  int m0 = blockIdx.y * 128, n0 = blockIdx.x * 128;
  int wm = (wave >> 1) * 64, wn = (wave & 1) * 64;
  f32x4 acc[4][4] = {};
  int srow = lane >> 2, scol = (lane & 3) * 8;           // staging: 4 lanes per 32-elem row
  int fro  = (lane & 15) * 32 + (lane >> 4) * 8;         // fragment read offset

  for (int k0 = 0; k0 < K; k0 += 32) {
    __syncthreads();
#pragma unroll
    for (int i = 0; i < 2; i++) {
      gload_lds16(A  + (size_t)(m0 + i*64 + wave*16 + srow) * K + k0 + scol, &As[(i*64 + wave*16) * 32]);
      gload_lds16(Bt + (size_t)(n0 + i*64 + wave*16 + srow) * K + k0 + scol, &Bs[(i*64 + wave*16) * 32]);
    }
    asm volatile("s_waitcnt vmcnt(0)" ::: "memory");
    __syncthreads();
    bf16x8 af[4], bfr[4];
#pragma unroll
    for (int i = 0; i < 4; i++) af[i]  = *reinterpret_cast<const bf16x8*>(&As[(wm + i*16)*32 + fro]);
#pragma unroll
    for (int j = 0; j < 4; j++) bfr[j] = *reinterpret_cast<const bf16x8*>(&Bs[(wn + j*16)*32 + fro]);
#pragma unroll
    for (int i = 0; i < 4; i++)
#pragma unroll
      for (int j = 0; j < 4; j++)
        acc[i][j] = __builtin_amdgcn_mfma_f32_16x16x32_bf16(af[i], bfr[j], acc[i][j], 0, 0, 0);
  }
  int rg = (lane >> 4) * 4, cq = lane & 15;
#pragma unroll
  for (int i = 0; i < 4; i++)
#pragma unroll
    for (int j = 0; j < 4; j++) {
      size_t basei = (size_t)(m0 + wm + i*16 + rg) * N + (size_t)(n0 + wn + j*16 + cq);
#pragma unroll
      for (int r = 0; r < 4; r++) {
        if constexpr (OUTF32) ((float*)Cv)[basei + (size_t)r * N] = acc[i][j][r];
        else                  ((u16*)Cv)[basei + (size_t)r * N]   = f2bf(acc[i][j][r]);
      }
    }
}

// ---------------- causal flash attention ----------------
// qkv: (B*T, 3C) bf16; per head h: Q cols [h*64), K cols [C+h*64), V cols [2C+h*64)
// Grid: (T/128=16, B*H). Block = 4 waves. Balanced causal split: block i covers
// query strips i and 31-i (64 rows each); waves 0,1 -> low strip, waves 2,3 -> high.
// Each wave: 32 queries (2 groups of 16). KV tile = 64 keys, staged in LDS.
__global__ __launch_bounds__(256) void attn_kernel(const u16* __restrict__ qkv, u16* __restrict__ attnout) {
  __shared__ u16 Ks[64*64];      // swizzled: byte = row*128 + ((col*2) ^ ((row&7)<<4))
  __shared__ u16 Vt[64*64];      // swizzled: elem = d*64 + (key ^ ((d&7)<<3))
  __shared__ u16 Pl[4*32*64];    // per-wave: elem = q*64 + (key ^ ((q&7)<<3))
  int tid = threadIdx.x, wave = tid >> 6, lane = tid & 63;
  int lq = lane & 15, lg = lane >> 4;
  int bh = blockIdx.y, b = bh >> 4, h = bh & 15;
  int pi = blockIdx.x;                    // pair index 0..15
  int strip = (wave < 2) ? pi : (31 - pi);
  int qbase = strip * 64 + (wave & 1) * 32;
  const u16* base = qkv + (size_t)b * T_ * N1_;

  // Q fragments: qf[qs][ch] lane l -> Q[qbase+qs*16+lq][ch*32 + lg*8 + j]
  bf16x8 qf[2][2];
#pragma unroll
  for (int qs = 0; qs < 2; qs++)
#pragma unroll
    for (int ch = 0; ch < 2; ch++)
      qf[qs][ch] = *reinterpret_cast<const bf16x8*>(
          base + (size_t)(qbase + qs*16 + lq) * N1_ + h*HD_ + ch*32 + lg*8);

  float m_run[2] = {-__builtin_inff(), -__builtin_inff()};
  float l_run[2] = {0.f, 0.f};
  f32x4 oacc[2][4] = {};

  // K staging: chunk c = wave*64+lane (+256); row=c>>3, cb=c&7; source col pre-swizzled
  int kc0 = wave*64 + lane;
  int krow0 = kc0 >> 3, kcb0 = kc0 & 7;
  const u16* ksrc0 = base + (size_t)krow0 * N1_ + C_ + h*HD_ + (kcb0 ^ (krow0 & 7)) * 8;
  int kc1 = kc0 + 256;
  int krow1 = kc1 >> 3, kcb1 = kc1 & 7;
  const u16* ksrc1 = base + (size_t)krow1 * N1_ + C_ + h*HD_ + (kcb1 ^ (krow1 & 7)) * 8;
  // V staging: thread handles keys (2kp, 2kp+1) x d[dc*8..+7]
  int vkp = lane & 31, vdc = wave*2 + (lane >> 5);
  const u16* vsrc = base + (size_t)(2*vkp) * N1_ + 2*C_ + h*HD_ + vdc*8;

  int nkt = 32 - pi;                      // tiles of 64 keys (bound = high strip's need)
  u32* Vt32 = reinterpret_cast<u32*>(Vt);

  for (int kt = 0; kt < nkt; kt++) {
    int kb = kt * 64;
    __syncthreads();
    gload_lds16(ksrc0 + (size_t)kb * N1_, (char*)Ks + wave*1024);
    gload_lds16(ksrc1 + (size_t)kb * N1_, (char*)Ks + 4096 + wave*1024);
    {
      bf16x8 va = *reinterpret_cast<const bf16x8*>(vsrc + (size_t)kb * N1_);
      bf16x8 vb = *reinterpret_cast<const bf16x8*>(vsrc + (size_t)kb * N1_ + N1_);
      const u16* au = (const u16*)&va;
      const u16* bu = (const u16*)&vb;
#pragma unroll
      for (int i = 0; i < 8; i++) {
        int d = vdc*8 + i;
        Vt32[d*32 + (((2*vkp) ^ (i<<3)) >> 1)] = (u32)au[i] | ((u32)bu[i] << 16);
      }
    }
    asm volatile("s_waitcnt vmcnt(0)" ::: "memory");
    __syncthreads();

    if (kb <= qbase + 31) {               // wave-uniform skip of fully-masked tiles
      // ---- QK^T: S^T[key][q] per key subtile ----
      f32x4 st[2][4];
#pragma unroll
      for (int sub = 0; sub < 4; sub++) {
        int krow = sub*16 + lq;
        bf16x8 kf0 = *reinterpret_cast<const bf16x8*>(&Ks[krow*64 + ((lg*8)      ^ ((lq&7)<<3))]);
        bf16x8 kf1 = *reinterpret_cast<const bf16x8*>(&Ks[krow*64 + ((32 + lg*8) ^ ((lq&7)<<3))]);
#pragma unroll
        for (int qs = 0; qs < 2; qs++) {
          f32x4 z = {0.f, 0.f, 0.f, 0.f};
          z = __builtin_amdgcn_mfma_f32_16x16x32_bf16(kf0, qf[qs][0], z, 0, 0, 0);
          z = __builtin_amdgcn_mfma_f32_16x16x32_bf16(kf1, qf[qs][1], z, 0, 0, 0);
          st[qs][sub] = z;
        }
      }
      // ---- online softmax per query group ----
      float resc[2];
#pragma unroll
      for (int qs = 0; qs < 2; qs++) {
        int qg = qbase + qs*16 + lq;
        float sc[4][4];
        float tmax = -__builtin_inff();
#pragma unroll
        for (int sub = 0; sub < 4; sub++)
#pragma unroll
          for (int r = 0; r < 4; r++) {
            float s = st[qs][sub][r] * 0.125f;
            int keyg = kb + sub*16 + lg*4 + r;
            if (keyg > qg) s = -__builtin_inff();
            sc[sub][r] = s;
            tmax = fmaxf(tmax, s);
          }
        tmax = fmaxf(tmax, __shfl_xor(tmax, 16));
        tmax = fmaxf(tmax, __shfl_xor(tmax, 32));
        float mnew = fmaxf(m_run[qs], tmax);
        resc[qs] = __expf(m_run[qs] - mnew);
        float tsum = 0.f;
        int qloc = qs*16 + lq;
#pragma unroll
        for (int sub = 0; sub < 4; sub++)
#pragma unroll
          for (int t2 = 0; t2 < 2; t2++) {
            float p0 = __expf(sc[sub][2*t2]   - mnew);
            float p1 = __expf(sc[sub][2*t2+1] - mnew);
            tsum += p0 + p1;
            int key0 = sub*16 + lg*4 + 2*t2;
            int el = qloc*64 + (key0 ^ ((lq&7)<<3));
            reinterpret_cast<u32*>(Pl)[wave*1024 + (el >> 1)] = (u32)f2bf(p0) | ((u32)f2bf(p1) << 16);
          }
        tsum += __shfl_xor(tsum, 16);
        tsum += __shfl_xor(tsum, 32);
        l_run[qs] = l_run[qs] * resc[qs] + tsum;
        m_run[qs] = mnew;
      }
      // ---- rescale O ----
#pragma unroll
      for (int qs = 0; qs < 2; qs++) {
        float rq[4];
#pragma unroll
        for (int r = 0; r < 4; r++) rq[r] = __shfl(resc[qs], lg*4 + r);
#pragma unroll
        for (int dt = 0; dt < 4; dt++)
#pragma unroll
          for (int r = 0; r < 4; r++) oacc[qs][dt][r] *= rq[r];
      }
      // ---- O += P * V ----
#pragma unroll
      for (int ks = 0; ks < 2; ks++) {
        int kcol = (ks*32 + lg*8) ^ ((lq&7)<<3);
        bf16x8 pa0 = *reinterpret_cast<const bf16x8*>(&Pl[wave*2048 + lq*64        + kcol]);
        bf16x8 pa1 = *reinterpret_cast<const bf16x8*>(&Pl[wave*2048 + (16+lq)*64   + kcol]);
#pragma unroll
        for (int dt = 0; dt < 4; dt++) {
          bf16x8 vf = *reinterpret_cast<const bf16x8*>(&Vt[(dt*16 + lq)*64 + kcol]);
          oacc[0][dt] = __builtin_amdgcn_mfma_f32_16x16x32_bf16(pa0, vf, oacc[0][dt], 0, 0, 0);
          oacc[1][dt] = __builtin_amdgcn_mfma_f32_16x16x32_bf16(pa1, vf, oacc[1][dt], 0, 0, 0);
        }
      }
    }
  }

  // ---- epilogue ----
#pragma unroll
  for (int qs = 0; qs < 2; qs++) {
    float linv[4];
#pragma unroll
    for (int r = 0; r < 4; r++) linv[r] = 1.f / __shfl(l_run[qs], lg*4 + r);
#pragma unroll
    for (int dt = 0; dt < 4; dt++)
#pragma unroll
      for (int r = 0; r < 4; r++) {
        size_t row = (size_t)(b*T_ + qbase + qs*16 + lg*4 + r);
        attnout[row * C_ + h*HD_ + dt*16 + lq] = f2bf(oacc[qs][dt][r] * linv[r]);
      }
  }
}

extern "C" void kernel_launch(void* const* d_in, const int* in_sizes, int n_in,
                              void* d_out, int out_size, void* d_ws, size_t ws_size,
                              hipStream_t stream) {
  const float* x     = (const float*)d_in[0];
  const float* w_qkv = (const float*)d_in[1];
  const float* w_out = (const float*)d_in[2];
  float* out = (float*)d_out;
  char* ws = (char*)d_ws;
  u16* xb    = (u16*)(ws);                         // 8 MB  : x bf16 (4096 x 1024)
  u16* wqkvT = (u16*)(ws + ((size_t)8  << 20));    // 6 MB  : w_qkv^T bf16 (3072 x 1024)
  u16* woutT = (u16*)(ws + ((size_t)14 << 20));    // 2 MB  : w_out^T bf16 (1024 x 1024)
  u16* qkvb  = (u16*)(ws + ((size_t)16 << 20));    // 24 MB : qkv bf16 (4096 x 3072)
  u16* attnb = (u16*)(ws + ((size_t)40 << 20));    // 8 MB  : attn out bf16 (4096 x 1024)

  cast_f32_bf16_k<<<(BT_*C_)/1024, 256, 0, stream>>>(x, xb, BT_*C_);
  transcast_k<<<dim3(N1_/32, C_/32), dim3(32, 8), 0, stream>>>(w_qkv, wqkvT, C_, N1_);
  transcast_k<<<dim3(C_/32, C_/32), dim3(32, 8), 0, stream>>>(w_out, woutT, C_, C_);
  gemm_bt<0><<<dim3(N1_/128, BT_/128), 256, 0, stream>>>(xb, wqkvT, (void*)qkvb, BT_, N1_, C_);
  attn_kernel<<<dim3(T_/128, B_*H_), 256, 0, stream>>>(qkvb, attnb);
  gemm_bt<1><<<dim3(C_/128, BT_/128), 256, 0, stream>>>(attnb, woutT, (void*)out, BT_, C_, C_);
}